// Round 1
// baseline (2395.806 us; speedup 1.0000x reference)
//
#include <hip/hip_runtime.h>
#include <math.h>

#define BATCH 2
#define SEQ   2048
#define DIM   1024
#define NHEAD 16
#define HD    64

// ---------------------------------------------------------------------------
// GEMM 1: fused QKV projection + RoPE.
// C = x @ W^T for W in {wq, wk, wv}; output layout [B*S, DIM] (== [B,S,NH,HD]).
// Tiling: 128x128 output tile, BK=16, 256 threads, 8x8 microtile per thread.
// LDS tiles stored transposed [k][row] so fragment reads are float4.
// ---------------------------------------------------------------------------
__global__ __launch_bounds__(256) void gemm_qkv_rope(
    const float* __restrict__ x,
    const float* __restrict__ wq, const float* __restrict__ wk,
    const float* __restrict__ wv,
    const float* __restrict__ fcos, const float* __restrict__ fsin,
    float* __restrict__ qout, float* __restrict__ kout, float* __restrict__ vout)
{
    __shared__ float As[16][132];
    __shared__ float Bs[16][132];

    const int ct  = blockIdx.x;          // 0..23 (col tiles over 3*DIM)
    const int rt  = blockIdx.y;          // 0..31 (row tiles over B*S)
    const int mt  = ct >> 3;             // 0=q, 1=k, 2=v
    const int c0l = (ct & 7) * 128;      // col within the selected matrix
    const int r0  = rt * 128;
    const float* __restrict__ w = (mt == 0) ? wq : (mt == 1) ? wk : wv;

    const int tid = threadIdx.x;
    const int tr  = tid >> 4;            // 0..15
    const int tc  = tid & 15;            // 0..15

    float acc[8][8];
#pragma unroll
    for (int i = 0; i < 8; ++i)
#pragma unroll
        for (int j = 0; j < 8; ++j) acc[i][j] = 0.f;

    for (int kt = 0; kt < DIM; kt += 16) {
#pragma unroll
        for (int l = 0; l < 2; ++l) {
            int idx = tid + l * 256;     // 0..511
            int row = idx >> 2;          // 0..127
            int kq  = idx & 3;           // float4 slot in 16 k's
            float4 av = *(const float4*)(x + (size_t)(r0 + row) * DIM + kt + kq * 4);
            As[kq * 4 + 0][row] = av.x;
            As[kq * 4 + 1][row] = av.y;
            As[kq * 4 + 2][row] = av.z;
            As[kq * 4 + 3][row] = av.w;
            float4 bv = *(const float4*)(w + (size_t)(c0l + row) * DIM + kt + kq * 4);
            Bs[kq * 4 + 0][row] = bv.x;
            Bs[kq * 4 + 1][row] = bv.y;
            Bs[kq * 4 + 2][row] = bv.z;
            Bs[kq * 4 + 3][row] = bv.w;
        }
        __syncthreads();
#pragma unroll
        for (int kk = 0; kk < 16; ++kk) {
            float4 a0 = *(const float4*)(&As[kk][tr * 8]);
            float4 a1 = *(const float4*)(&As[kk][tr * 8 + 4]);
            float4 b0 = *(const float4*)(&Bs[kk][tc * 8]);
            float4 b1 = *(const float4*)(&Bs[kk][tc * 8 + 4]);
            float a[8] = {a0.x, a0.y, a0.z, a0.w, a1.x, a1.y, a1.z, a1.w};
            float b[8] = {b0.x, b0.y, b0.z, b0.w, b1.x, b1.y, b1.z, b1.w};
#pragma unroll
            for (int i = 0; i < 8; ++i)
#pragma unroll
                for (int j = 0; j < 8; ++j)
                    acc[i][j] = fmaf(a[i], b[j], acc[i][j]);
        }
        __syncthreads();
    }

    float* __restrict__ outp = (mt == 0) ? qout : (mt == 1) ? kout : vout;
    const int colbase = c0l + tc * 8;
    const int d0 = colbase & (HD - 1);   // 8-aligned offset within head
    const int i0 = d0 >> 1;              // rope pair base index

#pragma unroll
    for (int i = 0; i < 8; ++i) {
        int row  = r0 + tr * 8 + i;
        int srow = row & (SEQ - 1);
        float vv[8];
#pragma unroll
        for (int j = 0; j < 8; ++j) vv[j] = acc[i][j];
        if (mt < 2) {
#pragma unroll
            for (int p = 0; p < 4; ++p) {
                float c  = fcos[srow * (HD / 2) + i0 + p];
                float sn = fsin[srow * (HD / 2) + i0 + p];
                float a  = vv[2 * p];
                float bb = vv[2 * p + 1];
                vv[2 * p]     = a * c - bb * sn;
                vv[2 * p + 1] = a * sn + bb * c;
            }
        }
        float* dst = outp + (size_t)row * DIM + colbase;
        *(float4*)dst       = make_float4(vv[0], vv[1], vv[2], vv[3]);
        *((float4*)dst + 1) = make_float4(vv[4], vv[5], vv[6], vv[7]);
    }
}

// ---------------------------------------------------------------------------
// Attention: one block per (b, h, 32-row q tile). Two passes over K tiles:
// pass 1 = online row max & expsum; pass 2 = recompute scores, write the
// normalized weights to d_out, and accumulate O += P @ V.
// ---------------------------------------------------------------------------
__global__ __launch_bounds__(256) void attn_kernel(
    const float* __restrict__ Q, const float* __restrict__ K,
    const float* __restrict__ V,
    float* __restrict__ attnw, float* __restrict__ O)
{
    __shared__ float Qs[32][65];
    __shared__ float Ks[64][65];
    __shared__ float Vs[64][72];
    __shared__ float Ps[32][65];

    const int b  = blockIdx.z;
    const int h  = blockIdx.y;
    const int q0 = blockIdx.x * 32;
    const int tid = threadIdx.x;

    const int qg = tid >> 4;   // 0..15, owns q rows 2qg, 2qg+1
    const int kg = tid & 15;   // 0..15, owns k cols 4kg..4kg+3
    const int pr = tid & 31;   // PV: row 0..31
    const int pd = tid >> 5;   // PV: dim block 0..7 (8 dims each)

    const float* Qbase = Q + (size_t)b * SEQ * DIM + h * HD;
    const float* Kbase = K + (size_t)b * SEQ * DIM + h * HD;
    const float* Vbase = V + (size_t)b * SEQ * DIM + h * HD;

    for (int i = tid; i < 32 * 16; i += 256) {
        int row = i >> 4, f4 = i & 15;
        float4 v = *(const float4*)(Qbase + (size_t)(q0 + row) * DIM + f4 * 4);
        Qs[row][f4 * 4 + 0] = v.x; Qs[row][f4 * 4 + 1] = v.y;
        Qs[row][f4 * 4 + 2] = v.z; Qs[row][f4 * 4 + 3] = v.w;
    }

    float m[2] = {-1e30f, -1e30f};
    float l[2] = {0.f, 0.f};
    __syncthreads();

    const int qr0 = qg * 2, kr0 = kg * 4;

    // ---------------- pass 1: row max + expsum ----------------
    for (int kt = 0; kt < SEQ; kt += 64) {
        for (int i = tid; i < 64 * 16; i += 256) {
            int row = i >> 4, f4 = i & 15;
            float4 v = *(const float4*)(Kbase + (size_t)(kt + row) * DIM + f4 * 4);
            Ks[row][f4 * 4 + 0] = v.x; Ks[row][f4 * 4 + 1] = v.y;
            Ks[row][f4 * 4 + 2] = v.z; Ks[row][f4 * 4 + 3] = v.w;
        }
        __syncthreads();

        float sc0[4] = {0, 0, 0, 0}, sc1[4] = {0, 0, 0, 0};
#pragma unroll 8
        for (int d = 0; d < HD; ++d) {
            float q0v = Qs[qr0][d];
            float q1v = Qs[qr0 + 1][d];
#pragma unroll
            for (int j = 0; j < 4; ++j) {
                float kv = Ks[kr0 + j][d];
                sc0[j] = fmaf(q0v, kv, sc0[j]);
                sc1[j] = fmaf(q1v, kv, sc1[j]);
            }
        }
#pragma unroll
        for (int i = 0; i < 2; ++i) {
            float* sc = i ? sc1 : sc0;
#pragma unroll
            for (int j = 0; j < 4; ++j) sc[j] *= 0.125f;
            float tm = fmaxf(fmaxf(sc[0], sc[1]), fmaxf(sc[2], sc[3]));
            for (int off = 8; off; off >>= 1) tm = fmaxf(tm, __shfl_xor(tm, off, 16));
            float nm = fmaxf(m[i], tm);
            float ps = __expf(sc[0] - nm) + __expf(sc[1] - nm) +
                       __expf(sc[2] - nm) + __expf(sc[3] - nm);
            for (int off = 8; off; off >>= 1) ps += __shfl_xor(ps, off, 16);
            l[i] = l[i] * __expf(m[i] - nm) + ps;
            m[i] = nm;
        }
        __syncthreads();
    }

    const float invl[2] = {1.f / l[0], 1.f / l[1]};
    float o[8] = {0, 0, 0, 0, 0, 0, 0, 0};
    float* attnbase = attnw + ((size_t)(b * NHEAD + h) * SEQ + q0) * SEQ;

    // ---------------- pass 2: weights + PV ----------------
    for (int kt = 0; kt < SEQ; kt += 64) {
        for (int i = tid; i < 64 * 16; i += 256) {
            int row = i >> 4, f4 = i & 15;
            float4 v = *(const float4*)(Kbase + (size_t)(kt + row) * DIM + f4 * 4);
            Ks[row][f4 * 4 + 0] = v.x; Ks[row][f4 * 4 + 1] = v.y;
            Ks[row][f4 * 4 + 2] = v.z; Ks[row][f4 * 4 + 3] = v.w;
            float4 vv = *(const float4*)(Vbase + (size_t)(kt + row) * DIM + f4 * 4);
            Vs[row][f4 * 4 + 0] = vv.x; Vs[row][f4 * 4 + 1] = vv.y;
            Vs[row][f4 * 4 + 2] = vv.z; Vs[row][f4 * 4 + 3] = vv.w;
        }
        __syncthreads();

        float sc0[4] = {0, 0, 0, 0}, sc1[4] = {0, 0, 0, 0};
#pragma unroll 8
        for (int d = 0; d < HD; ++d) {
            float q0v = Qs[qr0][d];
            float q1v = Qs[qr0 + 1][d];
#pragma unroll
            for (int j = 0; j < 4; ++j) {
                float kv = Ks[kr0 + j][d];
                sc0[j] = fmaf(q0v, kv, sc0[j]);
                sc1[j] = fmaf(q1v, kv, sc1[j]);
            }
        }
#pragma unroll
        for (int i = 0; i < 2; ++i) {
            float* sc = i ? sc1 : sc0;
            float p0 = __expf(sc[0] * 0.125f - m[i]) * invl[i];
            float p1 = __expf(sc[1] * 0.125f - m[i]) * invl[i];
            float p2 = __expf(sc[2] * 0.125f - m[i]) * invl[i];
            float p3 = __expf(sc[3] * 0.125f - m[i]) * invl[i];
            Ps[qr0 + i][kr0 + 0] = p0; Ps[qr0 + i][kr0 + 1] = p1;
            Ps[qr0 + i][kr0 + 2] = p2; Ps[qr0 + i][kr0 + 3] = p3;
            *(float4*)(attnbase + (size_t)(qr0 + i) * SEQ + kt + kr0) =
                make_float4(p0, p1, p2, p3);
        }
        __syncthreads();

#pragma unroll 8
        for (int k = 0; k < 64; ++k) {
            float p = Ps[pr][k];
            float4 v0 = *(const float4*)(&Vs[k][pd * 8]);
            float4 v1 = *(const float4*)(&Vs[k][pd * 8 + 4]);
            o[0] = fmaf(p, v0.x, o[0]); o[1] = fmaf(p, v0.y, o[1]);
            o[2] = fmaf(p, v0.z, o[2]); o[3] = fmaf(p, v0.w, o[3]);
            o[4] = fmaf(p, v1.x, o[4]); o[5] = fmaf(p, v1.y, o[5]);
            o[6] = fmaf(p, v1.z, o[6]); o[7] = fmaf(p, v1.w, o[7]);
        }
        __syncthreads();
    }

    float* Op = O + (size_t)(b * SEQ + q0 + pr) * DIM + h * HD + pd * 8;
    *(float4*)Op       = make_float4(o[0], o[1], o[2], o[3]);
    *((float4*)Op + 1) = make_float4(o[4], o[5], o[6], o[7]);
}

// ---------------------------------------------------------------------------
// GEMM 3: out = O @ wo^T. Same tiling as GEMM 1 without rope / matrix select.
// ---------------------------------------------------------------------------
__global__ __launch_bounds__(256) void gemm_wo(
    const float* __restrict__ A, const float* __restrict__ W,
    float* __restrict__ out)
{
    __shared__ float As[16][132];
    __shared__ float Bs[16][132];

    const int c0 = blockIdx.x * 128;     // 0..7 tiles over DIM
    const int r0 = blockIdx.y * 128;
    const int tid = threadIdx.x;
    const int tr = tid >> 4, tc = tid & 15;

    float acc[8][8];
#pragma unroll
    for (int i = 0; i < 8; ++i)
#pragma unroll
        for (int j = 0; j < 8; ++j) acc[i][j] = 0.f;

    for (int kt = 0; kt < DIM; kt += 16) {
#pragma unroll
        for (int l = 0; l < 2; ++l) {
            int idx = tid + l * 256;
            int row = idx >> 2;
            int kq  = idx & 3;
            float4 av = *(const float4*)(A + (size_t)(r0 + row) * DIM + kt + kq * 4);
            As[kq * 4 + 0][row] = av.x;
            As[kq * 4 + 1][row] = av.y;
            As[kq * 4 + 2][row] = av.z;
            As[kq * 4 + 3][row] = av.w;
            float4 bv = *(const float4*)(W + (size_t)(c0 + row) * DIM + kt + kq * 4);
            Bs[kq * 4 + 0][row] = bv.x;
            Bs[kq * 4 + 1][row] = bv.y;
            Bs[kq * 4 + 2][row] = bv.z;
            Bs[kq * 4 + 3][row] = bv.w;
        }
        __syncthreads();
#pragma unroll
        for (int kk = 0; kk < 16; ++kk) {
            float4 a0 = *(const float4*)(&As[kk][tr * 8]);
            float4 a1 = *(const float4*)(&As[kk][tr * 8 + 4]);
            float4 b0 = *(const float4*)(&Bs[kk][tc * 8]);
            float4 b1 = *(const float4*)(&Bs[kk][tc * 8 + 4]);
            float a[8] = {a0.x, a0.y, a0.z, a0.w, a1.x, a1.y, a1.z, a1.w};
            float b[8] = {b0.x, b0.y, b0.z, b0.w, b1.x, b1.y, b1.z, b1.w};
#pragma unroll
            for (int i = 0; i < 8; ++i)
#pragma unroll
                for (int j = 0; j < 8; ++j)
                    acc[i][j] = fmaf(a[i], b[j], acc[i][j]);
        }
        __syncthreads();
    }

#pragma unroll
    for (int i = 0; i < 8; ++i) {
        int row = r0 + tr * 8 + i;
        float* dst = out + (size_t)row * DIM + c0 + tc * 8;
        *(float4*)dst       = make_float4(acc[i][0], acc[i][1], acc[i][2], acc[i][3]);
        *((float4*)dst + 1) = make_float4(acc[i][4], acc[i][5], acc[i][6], acc[i][7]);
    }
}

extern "C" void kernel_launch(void* const* d_in, const int* in_sizes, int n_in,
                              void* d_out, int out_size, void* d_ws, size_t ws_size,
                              hipStream_t stream) {
    const float* x    = (const float*)d_in[0];
    const float* wq   = (const float*)d_in[1];
    const float* wk   = (const float*)d_in[2];
    const float* wv   = (const float*)d_in[3];
    const float* wo   = (const float*)d_in[4];
    const float* fcos = (const float*)d_in[5];
    const float* fsin = (const float*)d_in[6];

    float* out   = (float*)d_out;                       // [B,S,DIM]
    float* attnw = out + (size_t)BATCH * SEQ * DIM;     // [B,NH,S,S]

    const size_t tensz = (size_t)BATCH * SEQ * DIM;     // 4M floats
    float* qws = (float*)d_ws;
    float* kws = qws + tensz;
    float* vws = kws + tensz;
    float* ows = vws + tensz;

    dim3 g1(24, 32);
    gemm_qkv_rope<<<g1, 256, 0, stream>>>(x, wq, wk, wv, fcos, fsin, qws, kws, vws);

    dim3 g2(SEQ / 32, NHEAD, BATCH);
    attn_kernel<<<g2, 256, 0, stream>>>(qws, kws, vws, attnw, ows);

    dim3 g3(DIM / 128, 32);
    gemm_wo<<<g3, 256, 0, stream>>>(ows, wo, out);
}